// Round 1
// baseline (237.297 us; speedup 1.0000x reference)
//
#include <hip/hip_runtime.h>

// SSIM, fused: reflect-pad(1) + five 3x3 box filters + elementwise formula.
// NCHW 32x3x384x640 fp32. Memory-bound; design target = 1x read of x,y + 1x write.
//
// Each thread owns one column w and walks KROWS rows, keeping a rolling
// 3-row window of horizontal 3-tap sums (x, y, x^2, y^2, xy) in registers:
// 6 loads per new row instead of 18 per pixel.

constexpr int HH = 384;
constexpr int WW = 640;
constexpr int KROWS = 16;          // rows per thread; halo amortization 18/16
constexpr int BW = 128;            // threads per block along w (640 = 5*128)
constexpr float C1 = 0.01f * 0.01f;
constexpr float C2 = 0.03f * 0.03f;

__global__ __launch_bounds__(BW) void ssim_kernel(
    const float* __restrict__ x,
    const float* __restrict__ y,
    float* __restrict__ out)
{
    const int w  = blockIdx.x * BW + threadIdx.x;
    const int h0 = blockIdx.y * KROWS;
    const size_t pbase = (size_t)blockIdx.z * (size_t)(HH * WW);
    const float* __restrict__ xp = x + pbase;
    const float* __restrict__ yp = y + pbase;
    float* __restrict__ op = out + pbase;

    // reflect (jnp 'reflect': edge NOT repeated): -1 -> 1, W -> W-2
    const int wm = (w == 0)      ? 1      : (w - 1);
    const int wq = (w == WW - 1) ? WW - 2 : (w + 1);

    float hx[3], hy[3], hxx[3], hyy[3], hxy[3];

#define LOAD_ROW(R, J) do {                                             \
        int rr = (R);                                                   \
        rr = (rr < 0) ? 1 : ((rr >= HH) ? (HH - 2) : rr);               \
        const float* __restrict__ xr = xp + (size_t)rr * WW;            \
        const float* __restrict__ yr = yp + (size_t)rr * WW;            \
        const float x0 = xr[wm], x1 = xr[w], x2 = xr[wq];               \
        const float y0 = yr[wm], y1 = yr[w], y2 = yr[wq];               \
        hx[J]  = x0 + x1 + x2;                                          \
        hy[J]  = y0 + y1 + y2;                                          \
        hxx[J] = x0 * x0 + x1 * x1 + x2 * x2;                           \
        hyy[J] = y0 * y0 + y1 * y1 + y2 * y2;                           \
        hxy[J] = x0 * y0 + x1 * y1 + x2 * y2;                           \
    } while (0)

    LOAD_ROW(h0 - 1, 0);
    LOAD_ROW(h0,     1);

    const float inv9 = 1.0f / 9.0f;

#pragma unroll
    for (int i = 0; i < KROWS; ++i) {
        const int h = h0 + i;
        LOAD_ROW(h + 1, (i + 2) % 3);

        const float sx  = hx[0]  + hx[1]  + hx[2];
        const float sy  = hy[0]  + hy[1]  + hy[2];
        const float sxx = hxx[0] + hxx[1] + hxx[2];
        const float syy = hyy[0] + hyy[1] + hyy[2];
        const float sxy = hxy[0] + hxy[1] + hxy[2];

        const float mux = sx * inv9;
        const float muy = sy * inv9;
        const float varx = sxx * inv9 - mux * mux;
        const float vary = syy * inv9 - muy * muy;
        const float cov  = sxy * inv9 - mux * muy;

        const float num = (2.0f * mux * muy + C1) * (2.0f * cov + C2);
        const float den = (mux * mux + muy * muy + C1) * (varx + vary + C2);
        float s = num / den;
        s = fminf(fmaxf(s, 0.0f), 1.0f);

        op[(size_t)h * WW + w] = s;
    }
#undef LOAD_ROW
}

extern "C" void kernel_launch(void* const* d_in, const int* in_sizes, int n_in,
                              void* d_out, int out_size, void* d_ws, size_t ws_size,
                              hipStream_t stream) {
    const float* x = (const float*)d_in[0];
    const float* y = (const float*)d_in[1];
    float* out = (float*)d_out;

    const int planes = in_sizes[0] / (HH * WW);   // 32*3 = 96
    dim3 grid(WW / BW, HH / KROWS, planes);       // (5, 24, 96)
    dim3 block(BW);
    ssim_kernel<<<grid, block, 0, stream>>>(x, y, out);
}